// Round 5
// baseline (1424.298 us; speedup 1.0000x reference)
//
#include <hip/hip_runtime.h>

typedef unsigned int uint;
typedef __bf16 bf16_t;
typedef bf16_t bf16x8 __attribute__((ext_vector_type(8)));
typedef float floatx4 __attribute__((ext_vector_type(4)));

struct __align__(8) us4 { unsigned short x, y, z, w; };

__device__ __forceinline__ unsigned short f2b(float f) {
    unsigned u = __float_as_uint(f);
    u = u + 0x7FFFu + ((u >> 16) & 1u);   // RNE
    return (unsigned short)(u >> 16);
}
__device__ __forceinline__ float b2f(unsigned short h) {
    return __uint_as_float(((unsigned)h) << 16);
}

// async global->LDS, 16B per lane; LDS dest is wave-uniform base + lane*16
__device__ __forceinline__ void g2l16(const void* g, void* l) {
    __builtin_amdgcn_global_load_lds((__attribute__((address_space(1))) void*)g,
                                     (__attribute__((address_space(3))) void*)l,
                                     16, 0, 0);
}

// ---------------------------------------------------------------------------
// gemmA: O[m,n] = sum_k A[m,k]*B[n,k], K=512 fixed (16 K-tiles of BK=32).
// Tile (MI*32) x 256, 512 threads = 8 waves (2M x 4N), wave-tile (MI*16)x64,
// acc[MI][4]. MI=8 -> 256x256 (qkv), MI=4 -> 128x256 (rest).
//
// R5: A-operand direct global->VGPR, SOFTWARE-PIPELINED 2 TILES AHEAD in
// registers (af0/af1 by tile parity); B through 4-deep B-only LDS ring
// (16KB/buf, 64KB -> 2 blocks/CU). R4's failure was issue order: af issued
// after STG made every MFMA's auto-wait drain the prefetch stages (vmcnt
// retires oldest-first). Fixed order per iter t:
//   STG B(t+2) | ds_read bv | MFMA(t) [auto-wait vmcnt(MI+4): retires only
//   af(t), 2 iters old] | afload(t+2) into af(t-parity regs, just consumed)
//   | vmcnt(2MI+2) [retires only B(t+1), 1 iter old] | s_barrier
// Steady-state queue: {B(t+1), af(t+1), B(t+2), af(t+2)} -- no wait drains.
// Tail: t=14 waits vmcnt(MI) (retire B(15)); t=15 plain MFMA, no barrier.
// Race-safety: STG(t+2) targets buf (t-2)&3, last ds_read 2 barriers ago.
//
// LDS buffer: 256 B-rows x 64B; 16B-chunk swizzle chunk' = chunk ^
// ((row>>1)&3) -> 2-way banks (free, verified 0 conflicts R3/R4). Stage
// keeps linear LDS dest; SOURCE pre-swizzled; ds_read applies the XOR.
//
// A-direct: lane l, frag i reads 16B at A[(wm+i*16+(l&15))*LD + (l>>4)*8
// + t*32] -- 16 rows x 64B segments; x4 cross-wave re-read served by L1/L2
// (R4 counters: FETCH_SIZE unchanged vs LDS-staged A). All n-tiles of an
// m-stripe land on one XCD (swizzle keeps xcd fixed) -> A re-reads L2-local.
//
// Grid (MODE != 6): 1-D, XCD swizzle id&7, g=id>>3, nt=g%NTN, ms=(g/NTN)*8+xcd.
// BMS: ms decodes (batch = ms&7, mtile = ms>>3) -> batch pinned to XCD.
// MODE 0: bf16 store
// MODE 3: f32 store of acc + R (residual)
// MODE 5: bf16 store of acc*(scale/Sn[row]) + R   (attn: fused q-softmax)
// MODE 4: fused qkv, B=concat(Wq,Wk,Wv)[1536x512]:
//   n0<512    : store exp(acc) -> O (=eq), atomicAdd row sums into Sq[m]
//   512..1023 : store exp(acc) transposed -> O2 (=ekT[b,d,n]), atomicAdd
//               column sums into Sk[b*512+d]
//   >=1024    : store acc transposed -> O3 (=vT[b,e,n])
// MODE 6: ctx split-K partial (MI=4). grid 512: xcd=id&7, g=id>>3; t8=g&7 ->
//   mt=t8>>1 (0..3), ntc=t8&1; slice=(g>>3)*8+xcd = b*8+sk (XCD-pinned).
//   A=vT[b, mt*128.., sk*512..], B=kT[b, ntc*256.., sk*512..], f32 store of
//   the 128x256 partial into P[slice*262144 + (mt*128+r)*512 + ntc*256 + c].
// ---------------------------------------------------------------------------
template <int MODE, int NTN, bool BMS, int LD, int MI>
__global__ __launch_bounds__(512, 4) void gemmA(
    const unsigned short* __restrict__ A, const unsigned short* __restrict__ B,
    void* __restrict__ O, const unsigned short* __restrict__ R,
    unsigned short* __restrict__ O2, unsigned short* __restrict__ O3,
    float* __restrict__ Sq, float* __restrict__ Sk,
    const float* __restrict__ Sn,
    long long sB, float scale)
{
    __shared__ __attribute__((aligned(16))) unsigned short Ls[4][8192]; // 64 KB

    const uint id = blockIdx.x;
    const int tid = threadIdx.x;
    const int l = tid & 63;
    const int w = tid >> 6;
    const int wm = (w >> 2) * (MI * 16);  // M-half of the tile
    const int wnb = (w & 3) * 64;         // 0..192 : N-strip of 256 cols

    int arow0 = 0, n0 = 0, bb = 0;
    const unsigned short* Ab;
    const unsigned short* Bbp;
    long long pbase = 0;

    if constexpr (MODE == 6) {
        const uint xcd = id & 7;
        const uint g = id >> 3;
        const int t8 = (int)(g & 7);
        const int mt = t8 >> 1, ntc = t8 & 1;
        const int slice = (int)(g >> 3) * 8 + (int)xcd;   // = b*8 + sk
        const int b6 = slice >> 3, sk6 = slice & 7;
        Ab  = A + ((long long)b6 * 512 + mt  * 128) * 4096 + sk6 * 512;
        Bbp = B + ((long long)b6 * 512 + ntc * 256) * 4096 + sk6 * 512;
        pbase = (long long)slice * 262144 + (long long)mt * 128 * 512 + ntc * 256;
    } else {
        const uint xcd = id & 7;
        const uint g = id >> 3;
        const uint nt = g % NTN;
        const uint mg = g / NTN;
        const uint ms = mg * 8 + xcd;
        if constexpr (BMS) { bb = (int)(ms & 7); arow0 = bb * 4096 + (int)(ms >> 3) * (MI * 32); }
        else               { bb = 0;             arow0 = (int)ms * (MI * 32); }
        n0 = (int)nt * 256;
        Ab  = A + (long long)arow0 * LD;
        Bbp = B + (long long)bb * sB + (long long)n0 * LD;
    }

    // ---- B staging sources (pre-swizzled): thread owns LDS 16B chunks
    // {tid, tid+512}; chunk p (row p>>2, slot p&3) holds source chunk
    // (p&3) ^ ((p>>3)&3). Second chunk: row+128, same slot/swizzle.
    const int q_ = tid >> 2;                         // 0..127
    const int lc = (tid & 3) ^ ((tid >> 3) & 3);
    const unsigned short* pB1 = Bbp + (long long)q_ * LD + lc * 8;
    const unsigned short* pB2 = pB1 + (long long)128 * LD;

#define STG(bi, koff) do {                                                  \
        unsigned short* d_ = &Ls[bi][0] + tid * 8;                          \
        g2l16(pB1 + (koff), d_);                                            \
        g2l16(pB2 + (koff), d_ + 4096);                                     \
    } while (0)

    // ---- fragment addressing
    const int fr = l & 15;
    const int c0 = l >> 4;
    const unsigned short* pAf = Ab + (long long)(wm + fr) * LD + c0 * 8;
    const int swz = (c0 ^ ((fr >> 1) & 3)) << 4;
    const int boff = (wnb + fr) * 64 + swz;          // + j*1024 (j<4)

    floatx4 acc[MI][4] = {};
    bf16x8 af0[MI], af1[MI];

    // waits: steady retires only B(t+1) (keep af(t+1)+B(t+2)+af(t+2) =
    // 2MI+2); tail retires B(15) (keep af(15) = MI).
#define VMW_STEADY do { if constexpr (MI == 8)                              \
        asm volatile("s_waitcnt vmcnt(18)" ::: "memory");                   \
    else asm volatile("s_waitcnt vmcnt(10)" ::: "memory"); } while (0)
#define VMW_TAIL do { if constexpr (MI == 8)                                \
        asm volatile("s_waitcnt vmcnt(8)" ::: "memory");                    \
    else asm volatile("s_waitcnt vmcnt(4)" ::: "memory"); } while (0)

#define BODY(T, AF, DO_NEXT, VMW)                                           \
    {                                                                       \
        if (DO_NEXT) STG((T + 2) & 3, (T + 2) * 32);                        \
        const char* Lb = (const char*)&Ls[(T) & 3][0];                      \
        bf16x8 bv[4];                                                       \
        _Pragma("unroll")                                                   \
        for (int j = 0; j < 4; ++j)                                         \
            bv[j] = *(const bf16x8*)(Lb + boff + j * 1024);                 \
        __builtin_amdgcn_s_setprio(1);                                      \
        _Pragma("unroll")                                                   \
        for (int i = 0; i < MI; ++i)                                        \
            _Pragma("unroll")                                               \
            for (int j = 0; j < 4; ++j)                                     \
                acc[i][j] = __builtin_amdgcn_mfma_f32_16x16x32_bf16(        \
                    AF[i], bv[j], acc[i][j], 0, 0, 0);                      \
        __builtin_amdgcn_s_setprio(0);                                      \
        if (DO_NEXT) {                                                      \
            _Pragma("unroll")                                               \
            for (int i = 0; i < MI; ++i)                                    \
                AF[i] = *(const bf16x8*)(pAf + (long long)i * 16 * LD       \
                                         + (T + 2) * 32);                   \
        }                                                                   \
        VMW;                                                                \
        __builtin_amdgcn_s_barrier();                                       \
    }

    // prologue: B(0), B(1), af(0), af(1); retire B(0); barrier
    STG(0, 0);
    STG(1, 32);
#pragma unroll
    for (int i = 0; i < MI; ++i)
        af0[i] = *(const bf16x8*)(pAf + (long long)i * 16 * LD);
#pragma unroll
    for (int i = 0; i < MI; ++i)
        af1[i] = *(const bf16x8*)(pAf + (long long)i * 16 * LD + 32);
    VMW_STEADY;
    __builtin_amdgcn_s_barrier();

    for (int t = 0; t < 14; t += 2) {
        BODY(t, af0, 1, VMW_STEADY);
        BODY(t + 1, af1, 1, VMW_STEADY);
    }
    BODY(14, af0, 0, VMW_TAIL);
    {   // t = 15: last tile, af1 holds A(15), buf 3; no trailing sync
        const char* Lb = (const char*)&Ls[3][0];
        bf16x8 bv[4];
#pragma unroll
        for (int j = 0; j < 4; ++j)
            bv[j] = *(const bf16x8*)(Lb + boff + j * 1024);
        __builtin_amdgcn_s_setprio(1);
#pragma unroll
        for (int i = 0; i < MI; ++i)
#pragma unroll
            for (int j = 0; j < 4; ++j)
                acc[i][j] = __builtin_amdgcn_mfma_f32_16x16x32_bf16(
                    af1[i], bv[j], acc[i][j], 0, 0, 0);
        __builtin_amdgcn_s_setprio(0);
    }
#undef BODY
#undef STG
#undef VMW_STEADY
#undef VMW_TAIL

    // C/D layout (verified m89/m91): col = lane&15, row = (lane>>4)*4 + reg
    const int col = l & 15;
    const int rbase = (l >> 4) * 4;
    const int gm0 = arow0 + wm + rbase;           // + i*16 + r
    const int gn0 = n0 + wnb + col;               // + j*16

    if constexpr (MODE == 6) {
        float* Pb = (float*)O + pbase;
#pragma unroll
        for (int i = 0; i < MI; ++i) {
            int lr = wm + i * 16 + rbase;
#pragma unroll
            for (int j = 0; j < 4; ++j) {
                int lcc = wnb + j * 16 + col;
#pragma unroll
                for (int r = 0; r < 4; ++r)
                    Pb[(long long)(lr + r) * 512 + lcc] = acc[i][j][r];
            }
        }
    } else if constexpr (MODE == 4) {
        if (n0 < 512) {
            // q branch: store exp, row-sum atomics
            unsigned short* Oq = (unsigned short*)O;
            float rs[MI][4];
#pragma unroll
            for (int i = 0; i < MI; ++i)
#pragma unroll
                for (int r = 0; r < 4; ++r) rs[i][r] = 0.f;
#pragma unroll
            for (int i = 0; i < MI; ++i) {
                int gm = gm0 + i * 16;
#pragma unroll
                for (int j = 0; j < 4; ++j) {
                    int gn = gn0 + j * 16;
#pragma unroll
                    for (int r = 0; r < 4; ++r) {
                        float e = __expf(acc[i][j][r]);
                        rs[i][r] += e;
                        Oq[(long long)(gm + r) * 512 + gn] = f2b(e);
                    }
                }
            }
#pragma unroll
            for (int i = 0; i < MI; ++i)
#pragma unroll
                for (int r = 0; r < 4; ++r) {
                    float v = rs[i][r];
                    v += __shfl_xor(v, 1);
                    v += __shfl_xor(v, 2);
                    v += __shfl_xor(v, 4);
                    v += __shfl_xor(v, 8);
                    if ((l & 15) == 0)
                        atomicAdd(&Sq[gm0 + i * 16 + r], v);
                }
        } else if (n0 < 1024) {
            // k branch: store exp transposed, column-sum atomics
            const int b = arow0 >> 12;
            const int mq0 = (arow0 & 4095) + wm + rbase;
            float cs[4] = {0.f, 0.f, 0.f, 0.f};
#pragma unroll
            for (int i = 0; i < MI; ++i) {
                int mq = mq0 + i * 16;
#pragma unroll
                for (int j = 0; j < 4; ++j) {
                    int d = gn0 + j * 16 - 512;
                    float e0 = __expf(acc[i][j][0]);
                    float e1 = __expf(acc[i][j][1]);
                    float e2 = __expf(acc[i][j][2]);
                    float e3 = __expf(acc[i][j][3]);
                    cs[j] += e0 + e1 + e2 + e3;
                    us4 pk = { f2b(e0), f2b(e1), f2b(e2), f2b(e3) };
                    *(us4*)(O2 + ((long long)b * 512 + d) * 4096 + mq) = pk;
                }
            }
#pragma unroll
            for (int j = 0; j < 4; ++j) {
                float v = cs[j];
                v += __shfl_xor(v, 16);
                v += __shfl_xor(v, 32);
                if (l < 16)
                    atomicAdd(&Sk[b * 512 + gn0 + j * 16 - 512], v);
            }
        } else {
            // v branch: plain transposed store
            const int b = arow0 >> 12;
            const int mq0 = (arow0 & 4095) + wm + rbase;
#pragma unroll
            for (int i = 0; i < MI; ++i) {
                int mq = mq0 + i * 16;
#pragma unroll
                for (int j = 0; j < 4; ++j) {
                    int e_ = gn0 + j * 16 - 1024;
                    us4 pk = { f2b(acc[i][j][0]), f2b(acc[i][j][1]),
                               f2b(acc[i][j][2]), f2b(acc[i][j][3]) };
                    *(us4*)(O3 + ((long long)b * 512 + e_) * 4096 + mq) = pk;
                }
            }
        }
    } else if constexpr (MODE == 5) {
#pragma unroll
        for (int i = 0; i < MI; ++i) {
            int gm = gm0 + i * 16;
            float invs[4];
#pragma unroll
            for (int r = 0; r < 4; ++r) invs[r] = scale / Sn[gm + r];
#pragma unroll
            for (int j = 0; j < 4; ++j) {
                int gn = gn0 + j * 16;
#pragma unroll
                for (int r = 0; r < 4; ++r) {
                    long long idx = (long long)(gm + r) * 512 + gn;
                    ((unsigned short*)O)[idx] =
                        f2b(acc[i][j][r] * invs[r] + b2f(R[idx]));
                }
            }
        }
    } else {
#pragma unroll
        for (int i = 0; i < MI; ++i) {
            int gm = gm0 + i * 16;
#pragma unroll
            for (int j = 0; j < 4; ++j) {
                int gn = gn0 + j * 16;
#pragma unroll
                for (int r = 0; r < 4; ++r) {
                    long long idx = (long long)(gm + r) * 512 + gn;
                    float v = acc[i][j][r];
                    if constexpr (MODE == 0) {
                        ((unsigned short*)O)[idx] = f2b(v);
                    } else {
                        ((float*)O)[idx] = v + b2f(R[idx]);
                    }
                }
            }
        }
    }
}

// Sum 8 split-K partials, normalize by k-softmax denominator Sk[b*512+d],
// store bf16 ctxT[b, e, d]. P layout: [slice = b*8+sk][512 e][512 d] f32.
__global__ __launch_bounds__(256) void ctx_reduce(const float* __restrict__ P,
                                                  const float* __restrict__ Sk,
                                                  unsigned short* __restrict__ Ct)
{
    long long f = (long long)blockIdx.x * 256 + threadIdx.x;  // 524288 total
    long long base = f * 4;
    int b = (int)(base >> 18);
    int rem = (int)(base & 262143);          // e*512 + d
    int d = rem & 511;
    float4 s = {0.f, 0.f, 0.f, 0.f};
#pragma unroll
    for (int sp = 0; sp < 8; ++sp) {
        float4 v = *(const float4*)(P + (long long)(b * 8 + sp) * 262144 + rem);
        s.x += v.x; s.y += v.y; s.z += v.z; s.w += v.w;
    }
    float4 sk = *(const float4*)(Sk + b * 512 + d);
    us4 o = { f2b(s.x / sk.x), f2b(s.y / sk.y), f2b(s.z / sk.z), f2b(s.w / sk.w) };
    *(us4*)(Ct + (long long)b * 262144 + rem) = o;
}

// ---------------------------------------------------------------------------
// conversions / init
// ---------------------------------------------------------------------------
__global__ __launch_bounds__(256) void f32_to_bf16_k(const float* __restrict__ in,
                                                     unsigned short* __restrict__ out)
{
    long long i = ((long long)blockIdx.x * 256 + threadIdx.x) * 4;
    float4 v = *(const float4*)(in + i);
    us4 o = { f2b(v.x), f2b(v.y), f2b(v.z), f2b(v.w) };
    *(us4*)(out + i) = o;
}

struct WPtrs { const float* in[5]; unsigned short* out[5]; };
__global__ __launch_bounds__(256) void conv_weights(WPtrs p)
{
    int which = blockIdx.y;
    long long i = ((long long)blockIdx.x * 256 + threadIdx.x) * 4;
    float4 v = *(const float4*)(p.in[which] + i);
    us4 o = { f2b(v.x), f2b(v.y), f2b(v.z), f2b(v.w) };
    *(us4*)(p.out[which] + i) = o;
}

__global__ __launch_bounds__(256) void zero_f32(float* __restrict__ p)
{
    long long i = ((long long)blockIdx.x * 256 + threadIdx.x) * 4;
    *(float4*)(p + i) = make_float4(0.f, 0.f, 0.f, 0.f);
}

// ---------------------------------------------------------------------------
extern "C" void kernel_launch(void* const* d_in, const int* in_sizes, int n_in,
                              void* d_out, int out_size, void* d_ws, size_t ws_size,
                              hipStream_t stream)
{
    (void)in_sizes; (void)n_in; (void)out_size; (void)ws_size;
    const float* x  = (const float*)d_in[0];
    const float* Wq = (const float*)d_in[1];
    const float* Wk = (const float*)d_in[2];
    const float* Wv = (const float*)d_in[3];
    const float* W1 = (const float*)d_in[4];
    const float* W2 = (const float*)d_in[5];
    float* out = (float*)d_out;

    const int Bn = 8, N = 4096, C = 512;
    const long long M  = (long long)Bn * N;   // 32768
    const long long XE = M * C;               // 16,777,216 elements

    char* ws = (char*)d_ws;
    size_t off = 0;
    auto carve = [&](size_t bytes) -> void* {
        void* p = ws + off;
        off += (bytes + 255) & ~(size_t)255;
        return p;
    };

    unsigned short* xb   = (unsigned short*)carve(XE * 2);
    unsigned short* wcat = (unsigned short*)carve((size_t)3 * C * C * 2); // [Wq;Wk;Wv]
    unsigned short* w1b  = (unsigned short*)carve((size_t)C * C * 2);
    unsigned short* w2b  = (unsigned short*)carve((size_t)C * C * 2);
    unsigned short* q    = (unsigned short*)carve(XE * 2);   // exp(q)
    unsigned short* kT   = (unsigned short*)carve(XE * 2);   // exp(k) [b,d,n]
    unsigned short* vT   = (unsigned short*)carve(XE * 2);   // [b,e,n]
    unsigned short* ctxT = (unsigned short*)carve((size_t)Bn * C * C * 2); // [b,e,d]
    float* Ssum = (float*)carve((size_t)(M + Bn * C) * 4);   // Sq[M] ++ Sk[Bn*C]
    float* Sq = Ssum;
    float* Sk = Ssum + M;
    unsigned short* xr = kT;       // alias: kT dead after ctx gemm
    unsigned short* h  = vT;       // alias: vT dead after ctx gemm
    float* P = (float*)d_out;      // split-K partials (64 slices x 1MB = 64MB
                                   // = d_out): scratch until the final gemm
                                   // overwrites all of it

    // zero softmax-sum accumulators (36864 floats = 36 blocks x 256 x 4)
    zero_f32<<<dim3(36), 256, 0, stream>>>(Ssum);

    // dtype conversions
    f32_to_bf16_k<<<dim3((unsigned)(XE / 1024)), dim3(256), 0, stream>>>(x, xb);
    WPtrs wp = { { Wq, Wk, Wv, W1, W2 },
                 { wcat, wcat + C * C, wcat + 2 * C * C, w1b, w2b } };
    conv_weights<<<dim3((C * C) / 1024, 5), dim3(256), 0, stream>>>(wp);

    // fused q/k/v + exp + softmax-denominator atomics: M=32768, N=1536
    // 256x256 tiles: 128 m-tiles x 6 n-tiles = 768 blocks
    gemmA<4, 6, false, 512, 8><<<dim3(768), 512, 0, stream>>>(
        xb, wcat, q, nullptr, kT, vT, Sq, Sk, nullptr, 0, 0.f);

    // ctxT'[b,e,d] = sum_n vT[b,e,n] * ek[b,d,n]  (split-K=8 + reduce w/ 1/Sk)
    gemmA<6, 1, false, 4096, 4><<<dim3(512), 512, 0, stream>>>(
        vT, kT, P, nullptr, nullptr, nullptr, nullptr, nullptr, nullptr,
        0, 0.f);
    ctx_reduce<<<dim3(2048), 256, 0, stream>>>(P, Sk, ctxT);

    // xr[b,n,e] = (scale/Sq[n]) * sum_d eq[b,n,d]*ctxT[b,e,d] + x[b,n,e]
    gemmA<5, 2, true, 512, 4><<<dim3(512), 512, 0, stream>>>(
        q, ctxT, xr, xb, nullptr, nullptr, nullptr, nullptr, Sq,
        (long long)C * C, 0.044194173824159216f);

    // h = xr @ W1.T
    gemmA<0, 2, false, 512, 4><<<dim3(512), 512, 0, stream>>>(
        xr, w1b, h, nullptr, nullptr, nullptr, nullptr, nullptr, nullptr,
        0, 0.f);

    // out = h @ W2.T + xr   (fp32 output)
    gemmA<3, 2, false, 512, 4><<<dim3(512), 512, 0, stream>>>(
        h, w2b, out, xr, nullptr, nullptr, nullptr, nullptr, nullptr,
        0, 0.f);
}

// Round 6
// 319.851 us; speedup vs baseline: 4.4530x; 4.4530x over previous
//
#include <hip/hip_runtime.h>

typedef unsigned int uint;
typedef __bf16 bf16_t;
typedef bf16_t bf16x8 __attribute__((ext_vector_type(8)));
typedef float floatx4 __attribute__((ext_vector_type(4)));

struct __align__(8) us4 { unsigned short x, y, z, w; };

__device__ __forceinline__ unsigned short f2b(float f) {
    unsigned u = __float_as_uint(f);
    u = u + 0x7FFFu + ((u >> 16) & 1u);   // RNE
    return (unsigned short)(u >> 16);
}
__device__ __forceinline__ float b2f(unsigned short h) {
    return __uint_as_float(((unsigned)h) << 16);
}

// async global->LDS, 16B per lane; LDS dest is wave-uniform base + lane*16
__device__ __forceinline__ void g2l16(const void* g, void* l) {
    __builtin_amdgcn_global_load_lds((__attribute__((address_space(1))) void*)g,
                                     (__attribute__((address_space(3))) void*)l,
                                     16, 0, 0);
}

// ---------------------------------------------------------------------------
// gemm128 (R3-verified structure, restored verbatim): O[m,n] = sum_k
// A[m,k]*B[n,k], K=512 fixed (16 K-tiles of BK=32). 128x256 tile, 512
// threads = 8 waves (2M x 4N), wave-tile 64x64, acc[4][4].
// 3-deep LDS ring x 24KB = 72KB -> 2 blocks/CU; regs 64 VGPR + 64 AGPR =
// exactly the 128-reg class (4 waves/EU, no spill -- R5's lesson).
//
// Per K-tile t: { stage tile t+2 into buf (t+2)%3 (3 x g2l16/thread);
//   ds_read 8 x b128 frags; setprio(1); 16 MFMA; setprio(0);
//   vmcnt(3) (counted: t+2's 3 loads stay in flight); s_barrier }.
//
// LDS buffer: rows 0..127 = A rows, 128..383 = B rows; 64B/row (32 k-elems),
// 16B-chunk swizzle chunk' = chunk ^ ((row>>1)&3) -> 2-way banks (free,
// verified 0 conflicts R3/R4). Stage keeps linear LDS dest; SOURCE
// pre-swizzled with the same involution; ds_read applies the XOR.
//
// Grid (MODE != 6): 1-D, XCD swizzle id&7, g=id>>3, nt=g%NTN, ms=(g/NTN)*8+xcd.
// BMS: ms decodes (batch = ms&7, mtile = ms>>3) -> batch pinned to XCD.
// MODE 0: bf16 store
// MODE 3: f32 store of acc + R (residual)
// MODE 5: bf16 store of acc*(scale/Sn[row]) + R   (attn: fused q-softmax)
// MODE 4: fused qkv, B=concat(Wq,Wk,Wv)[1536x512]:
//   n0<512    : store exp(acc) -> O (=eq), atomicAdd row sums into Sq[m]
//   512..1023 : store exp(acc) transposed -> O2 (=ekT[b,d,n]), atomicAdd
//               column sums into Sk[b*512+d]
//   >=1024    : store acc transposed -> O3 (=vT[b,e,n])
// MODE 6: ctx split-K partial. grid 512: xcd=id&7, g=id>>3; t8=g&7 ->
//   mt=t8>>1 (0..3), ntc=t8&1; slice=(g>>3)*8+xcd = b*8+sk (XCD-pinned).
//   A=vT[b, mt*128.., sk*512..], B=kT[b, ntc*256.., sk*512..], f32 store of
//   the 128x256 partial into P[slice*262144 + (mt*128+r)*512 + ntc*256 + c].
// ---------------------------------------------------------------------------
template <int MODE, int NTN, bool BMS, int LD>
__global__ __launch_bounds__(512, 4) void gemm128(
    const unsigned short* __restrict__ A, const unsigned short* __restrict__ B,
    void* __restrict__ O, const unsigned short* __restrict__ R,
    unsigned short* __restrict__ O2, unsigned short* __restrict__ O3,
    float* __restrict__ Sq, float* __restrict__ Sk,
    const float* __restrict__ Sn,
    long long sB, float scale)
{
    __shared__ __attribute__((aligned(16))) unsigned short Ls[3][12288]; // 72 KB

    const uint id = blockIdx.x;
    const int tid = threadIdx.x;
    const int l = tid & 63;
    const int w = tid >> 6;
    const int wm = (w >> 2) * 64;     // 0/64   : M-half of the 128-row tile
    const int wnb = (w & 3) * 64;     // 0..192 : N-strip of the 256-col tile

    int arow0 = 0, n0 = 0, bb = 0;
    const unsigned short* Ab;
    const unsigned short* Bbp;
    long long pbase = 0;

    if constexpr (MODE == 6) {
        const uint xcd = id & 7;
        const uint g = id >> 3;
        const int t8 = (int)(g & 7);
        const int mt = t8 >> 1, ntc = t8 & 1;
        const int slice = (int)(g >> 3) * 8 + (int)xcd;   // = b*8 + sk
        const int b6 = slice >> 3, sk6 = slice & 7;
        Ab  = A + ((long long)b6 * 512 + mt  * 128) * 4096 + sk6 * 512;
        Bbp = B + ((long long)b6 * 512 + ntc * 256) * 4096 + sk6 * 512;
        pbase = (long long)slice * 262144 + (long long)mt * 128 * 512 + ntc * 256;
    } else {
        const uint xcd = id & 7;
        const uint g = id >> 3;
        const uint nt = g % NTN;
        const uint mg = g / NTN;
        const uint ms = mg * 8 + xcd;
        if constexpr (BMS) { bb = (int)(ms & 7); arow0 = bb * 4096 + (int)(ms >> 3) * 128; }
        else               { bb = 0;             arow0 = (int)ms * 128; }
        n0 = (int)nt * 256;
        Ab  = A + (long long)arow0 * LD;
        Bbp = B + (long long)bb * sB + (long long)n0 * LD;
    }

    // ---- staging sources (pre-swizzled): thread owns LDS 16B chunks
    // {tid, tid+512, tid+1024}; chunk p (row p>>2, slot p&3) holds source
    // chunk (p&3) ^ ((row>>1)&3). Rows 0..127 = A, 128..383 = B (row-128).
    const int q_ = tid >> 2;                         // 0..127
    const int lc = (tid & 3) ^ ((tid >> 3) & 3);
    const unsigned short* pA  = Ab  + (long long)q_ * LD + lc * 8;
    const unsigned short* pB1 = Bbp + (long long)q_ * LD + lc * 8;
    const unsigned short* pB2 = Bbp + (long long)(128 + q_) * LD + lc * 8;

#define STG(bi, koff) do {                                                  \
        unsigned short* d_ = &Ls[bi][0] + tid * 8;                          \
        g2l16(pA  + (koff), d_);                                            \
        g2l16(pB1 + (koff), d_ + 4096);                                     \
        g2l16(pB2 + (koff), d_ + 8192);                                     \
    } while (0)

    // ---- ds_read fragment addressing (byte offsets within a buffer)
    const int fr = l & 15;
    const int c0 = l >> 4;
    const int swz = (c0 ^ ((fr >> 1) & 3)) << 4;
    const int aoff = (wm + fr) * 64 + swz;            // + i*1024 (i<4)
    const int boff = (128 + wnb + fr) * 64 + swz;     // + j*1024 (j<4)

    floatx4 acc[4][4] = {};

    // prologue: tiles 0,1 staged; wait tile 0 (6 issued, keep 3 in flight)
    STG(0, 0);
    STG(1, 32);
    asm volatile("s_waitcnt vmcnt(3)" ::: "memory");
    __builtin_amdgcn_s_barrier();

    int cur = 0, stb = 2;
    for (int t = 0; t < 16; ++t) {
        if (t + 2 < 16) STG(stb, (t + 2) * 32);

        const char* Lb = (const char*)&Ls[cur][0];
        bf16x8 af[4], bv[4];
#pragma unroll
        for (int i = 0; i < 4; ++i) af[i] = *(const bf16x8*)(Lb + aoff + i * 1024);
#pragma unroll
        for (int j = 0; j < 4; ++j) bv[j] = *(const bf16x8*)(Lb + boff + j * 1024);

        __builtin_amdgcn_s_setprio(1);
#pragma unroll
        for (int i = 0; i < 4; ++i)
#pragma unroll
            for (int j = 0; j < 4; ++j)
                acc[i][j] = __builtin_amdgcn_mfma_f32_16x16x32_bf16(
                    af[i], bv[j], acc[i][j], 0, 0, 0);
        __builtin_amdgcn_s_setprio(0);

        if (t < 15) {
            if (t < 14) asm volatile("s_waitcnt vmcnt(3)" ::: "memory");
            else        asm volatile("s_waitcnt vmcnt(0)" ::: "memory");
            __builtin_amdgcn_s_barrier();
        }
        cur = (cur == 2) ? 0 : cur + 1;
        stb = (stb == 2) ? 0 : stb + 1;
    }
#undef STG

    // C/D layout (verified m89/m91): col = lane&15, row = (lane>>4)*4 + reg
    const int col = l & 15;
    const int rbase = (l >> 4) * 4;
    const int gm0 = arow0 + wm + rbase;           // + i*16 + r
    const int gn0 = n0 + wnb + col;               // + j*16

    if constexpr (MODE == 6) {
        float* Pb = (float*)O + pbase;
#pragma unroll
        for (int i = 0; i < 4; ++i) {
            int lr = wm + i * 16 + rbase;
#pragma unroll
            for (int j = 0; j < 4; ++j) {
                int lcc = wnb + j * 16 + col;
#pragma unroll
                for (int r = 0; r < 4; ++r)
                    Pb[(long long)(lr + r) * 512 + lcc] = acc[i][j][r];
            }
        }
    } else if constexpr (MODE == 4) {
        if (n0 < 512) {
            // q branch: store exp, row-sum atomics
            unsigned short* Oq = (unsigned short*)O;
            float rs[4][4];
#pragma unroll
            for (int i = 0; i < 4; ++i)
#pragma unroll
                for (int r = 0; r < 4; ++r) rs[i][r] = 0.f;
#pragma unroll
            for (int i = 0; i < 4; ++i) {
                int gm = gm0 + i * 16;
#pragma unroll
                for (int j = 0; j < 4; ++j) {
                    int gn = gn0 + j * 16;
#pragma unroll
                    for (int r = 0; r < 4; ++r) {
                        float e = __expf(acc[i][j][r]);
                        rs[i][r] += e;
                        Oq[(long long)(gm + r) * 512 + gn] = f2b(e);
                    }
                }
            }
#pragma unroll
            for (int i = 0; i < 4; ++i)
#pragma unroll
                for (int r = 0; r < 4; ++r) {
                    float v = rs[i][r];
                    v += __shfl_xor(v, 1);
                    v += __shfl_xor(v, 2);
                    v += __shfl_xor(v, 4);
                    v += __shfl_xor(v, 8);
                    if ((l & 15) == 0)
                        atomicAdd(&Sq[gm0 + i * 16 + r], v);
                }
        } else if (n0 < 1024) {
            // k branch: store exp transposed, column-sum atomics
            const int b = arow0 >> 12;
            const int mq0 = (arow0 & 4095) + wm + rbase;
            float cs[4] = {0.f, 0.f, 0.f, 0.f};
#pragma unroll
            for (int i = 0; i < 4; ++i) {
                int mq = mq0 + i * 16;
#pragma unroll
                for (int j = 0; j < 4; ++j) {
                    int d = gn0 + j * 16 - 512;
                    float e0 = __expf(acc[i][j][0]);
                    float e1 = __expf(acc[i][j][1]);
                    float e2 = __expf(acc[i][j][2]);
                    float e3 = __expf(acc[i][j][3]);
                    cs[j] += e0 + e1 + e2 + e3;
                    us4 pk = { f2b(e0), f2b(e1), f2b(e2), f2b(e3) };
                    *(us4*)(O2 + ((long long)b * 512 + d) * 4096 + mq) = pk;
                }
            }
#pragma unroll
            for (int j = 0; j < 4; ++j) {
                float v = cs[j];
                v += __shfl_xor(v, 16);
                v += __shfl_xor(v, 32);
                if (l < 16)
                    atomicAdd(&Sk[b * 512 + gn0 + j * 16 - 512], v);
            }
        } else {
            // v branch: plain transposed store
            const int b = arow0 >> 12;
            const int mq0 = (arow0 & 4095) + wm + rbase;
#pragma unroll
            for (int i = 0; i < 4; ++i) {
                int mq = mq0 + i * 16;
#pragma unroll
                for (int j = 0; j < 4; ++j) {
                    int e_ = gn0 + j * 16 - 1024;
                    us4 pk = { f2b(acc[i][j][0]), f2b(acc[i][j][1]),
                               f2b(acc[i][j][2]), f2b(acc[i][j][3]) };
                    *(us4*)(O3 + ((long long)b * 512 + e_) * 4096 + mq) = pk;
                }
            }
        }
    } else if constexpr (MODE == 5) {
#pragma unroll
        for (int i = 0; i < 4; ++i) {
            int gm = gm0 + i * 16;
            float invs[4];
#pragma unroll
            for (int r = 0; r < 4; ++r) invs[r] = scale / Sn[gm + r];
#pragma unroll
            for (int j = 0; j < 4; ++j) {
                int gn = gn0 + j * 16;
#pragma unroll
                for (int r = 0; r < 4; ++r) {
                    long long idx = (long long)(gm + r) * 512 + gn;
                    ((unsigned short*)O)[idx] =
                        f2b(acc[i][j][r] * invs[r] + b2f(R[idx]));
                }
            }
        }
    } else {
#pragma unroll
        for (int i = 0; i < 4; ++i) {
            int gm = gm0 + i * 16;
#pragma unroll
            for (int j = 0; j < 4; ++j) {
                int gn = gn0 + j * 16;
#pragma unroll
                for (int r = 0; r < 4; ++r) {
                    long long idx = (long long)(gm + r) * 512 + gn;
                    float v = acc[i][j][r];
                    if constexpr (MODE == 0) {
                        ((unsigned short*)O)[idx] = f2b(v);
                    } else {
                        ((float*)O)[idx] = v + b2f(R[idx]);
                    }
                }
            }
        }
    }
}

// ---------------------------------------------------------------------------
// Wg = W2 @ W1 (bf16 in, f32 accum, bf16 out). 512 blocks (one output row
// n each), 256 threads (thread t owns cols t and t+256). W1 rows are read
// coalesced (contiguous bf16 across lanes); W2[n,k] is wave-uniform (SGPR
// load). L2-resident inputs (1 MB) -> ~5-8 us. Enables the FFN fusion:
// (x@W1.T)@W2.T = x@Wg.T, eliminating one 32768x512x512 GEMM.
// ---------------------------------------------------------------------------
__global__ __launch_bounds__(256) void wg_gemm(
    const unsigned short* __restrict__ W2b, const unsigned short* __restrict__ W1b,
    unsigned short* __restrict__ Wg)
{
    const int n = blockIdx.x;
    const int t = threadIdx.x;
    float a0 = 0.f, a1 = 0.f;
    const unsigned short* w2r = W2b + n * 512;
#pragma unroll 4
    for (int k = 0; k < 512; ++k) {
        float s = b2f(w2r[k]);
        a0 += s * b2f(W1b[k * 512 + t]);
        a1 += s * b2f(W1b[k * 512 + t + 256]);
    }
    Wg[n * 512 + t]       = f2b(a0);
    Wg[n * 512 + t + 256] = f2b(a1);
}

// Sum 8 split-K partials, normalize by k-softmax denominator Sk[b*512+d],
// store bf16 ctxT[b, e, d]. P layout: [slice = b*8+sk][512 e][512 d] f32.
__global__ __launch_bounds__(256) void ctx_reduce(const float* __restrict__ P,
                                                  const float* __restrict__ Sk,
                                                  unsigned short* __restrict__ Ct)
{
    long long f = (long long)blockIdx.x * 256 + threadIdx.x;  // 524288 total
    long long base = f * 4;
    int b = (int)(base >> 18);
    int rem = (int)(base & 262143);          // e*512 + d
    int d = rem & 511;
    float4 s = {0.f, 0.f, 0.f, 0.f};
#pragma unroll
    for (int sp = 0; sp < 8; ++sp) {
        float4 v = *(const float4*)(P + (long long)(b * 8 + sp) * 262144 + rem);
        s.x += v.x; s.y += v.y; s.z += v.z; s.w += v.w;
    }
    float4 sk = *(const float4*)(Sk + b * 512 + d);
    us4 o = { f2b(s.x / sk.x), f2b(s.y / sk.y), f2b(s.z / sk.z), f2b(s.w / sk.w) };
    *(us4*)(Ct + (long long)b * 262144 + rem) = o;
}

// ---------------------------------------------------------------------------
// conversions / init
// ---------------------------------------------------------------------------
__global__ __launch_bounds__(256) void f32_to_bf16_k(const float* __restrict__ in,
                                                     unsigned short* __restrict__ out)
{
    long long i = ((long long)blockIdx.x * 256 + threadIdx.x) * 4;
    float4 v = *(const float4*)(in + i);
    us4 o = { f2b(v.x), f2b(v.y), f2b(v.z), f2b(v.w) };
    *(us4*)(out + i) = o;
}

struct WPtrs { const float* in[5]; unsigned short* out[5]; };
__global__ __launch_bounds__(256) void conv_weights(WPtrs p)
{
    int which = blockIdx.y;
    long long i = ((long long)blockIdx.x * 256 + threadIdx.x) * 4;
    float4 v = *(const float4*)(p.in[which] + i);
    us4 o = { f2b(v.x), f2b(v.y), f2b(v.z), f2b(v.w) };
    *(us4*)(p.out[which] + i) = o;
}

__global__ __launch_bounds__(256) void zero_f32(float* __restrict__ p)
{
    long long i = ((long long)blockIdx.x * 256 + threadIdx.x) * 4;
    *(float4*)(p + i) = make_float4(0.f, 0.f, 0.f, 0.f);
}

// ---------------------------------------------------------------------------
extern "C" void kernel_launch(void* const* d_in, const int* in_sizes, int n_in,
                              void* d_out, int out_size, void* d_ws, size_t ws_size,
                              hipStream_t stream)
{
    (void)in_sizes; (void)n_in; (void)out_size; (void)ws_size;
    const float* x  = (const float*)d_in[0];
    const float* Wq = (const float*)d_in[1];
    const float* Wk = (const float*)d_in[2];
    const float* Wv = (const float*)d_in[3];
    const float* W1 = (const float*)d_in[4];
    const float* W2 = (const float*)d_in[5];
    float* out = (float*)d_out;

    const int Bn = 8, N = 4096, C = 512;
    const long long M  = (long long)Bn * N;   // 32768
    const long long XE = M * C;               // 16,777,216 elements

    char* ws = (char*)d_ws;
    size_t off = 0;
    auto carve = [&](size_t bytes) -> void* {
        void* p = ws + off;
        off += (bytes + 255) & ~(size_t)255;
        return p;
    };

    unsigned short* xb   = (unsigned short*)carve(XE * 2);
    unsigned short* wcat = (unsigned short*)carve((size_t)3 * C * C * 2); // [Wq;Wk;Wv]
    unsigned short* w1b  = (unsigned short*)carve((size_t)C * C * 2);
    unsigned short* w2b  = (unsigned short*)carve((size_t)C * C * 2);
    unsigned short* wgb  = (unsigned short*)carve((size_t)C * C * 2);     // W2@W1
    unsigned short* q    = (unsigned short*)carve(XE * 2);   // exp(q)
    unsigned short* kT   = (unsigned short*)carve(XE * 2);   // exp(k) [b,d,n]
    unsigned short* vT   = (unsigned short*)carve(XE * 2);   // [b,e,n]
    unsigned short* ctxT = (unsigned short*)carve((size_t)Bn * C * C * 2); // [b,e,d]
    float* Ssum = (float*)carve((size_t)(M + Bn * C) * 4);   // Sq[M] ++ Sk[Bn*C]
    float* Sq = Ssum;
    float* Sk = Ssum + M;
    unsigned short* xr = kT;       // alias: kT dead after ctx gemm
    float* P = (float*)d_out;      // split-K partials (64 slices x 1MB = 64MB
                                   // = d_out): scratch until the final gemm
                                   // overwrites all of it

    // zero softmax-sum accumulators (36864 floats = 36 blocks x 256 x 4)
    zero_f32<<<dim3(36), 256, 0, stream>>>(Ssum);

    // dtype conversions
    f32_to_bf16_k<<<dim3((unsigned)(XE / 1024)), dim3(256), 0, stream>>>(x, xb);
    WPtrs wp = { { Wq, Wk, Wv, W1, W2 },
                 { wcat, wcat + C * C, wcat + 2 * C * C, w1b, w2b } };
    conv_weights<<<dim3((C * C) / 1024, 5), dim3(256), 0, stream>>>(wp);

    // Wg = W2 @ W1 (FFN fusion: (x@W1.T)@W2.T == x@(W2@W1).T)
    wg_gemm<<<dim3(512), 256, 0, stream>>>(w2b, w1b, wgb);

    // fused q/k/v + exp + softmax-denominator atomics: M=32768, N=1536
    // grid = 256 m-tiles x 6 n-tiles = 1536 (2 blocks/CU co-resident)
    gemm128<4, 6, false, 512><<<dim3(1536), 512, 0, stream>>>(
        xb, wcat, q, nullptr, kT, vT, Sq, Sk, nullptr, 0, 0.f);

    // ctxT'[b,e,d] = sum_n vT[b,e,n] * ek[b,d,n]  (split-K=8 + reduce w/ 1/Sk)
    gemm128<6, 1, false, 4096><<<dim3(512), 512, 0, stream>>>(
        vT, kT, P, nullptr, nullptr, nullptr, nullptr, nullptr, nullptr,
        0, 0.f);
    ctx_reduce<<<dim3(2048), 256, 0, stream>>>(P, Sk, ctxT);

    // xr[b,n,e] = (scale/Sq[n]) * sum_d eq[b,n,d]*ctxT[b,e,d] + x[b,n,e]
    gemm128<5, 2, true, 512><<<dim3(512), 512, 0, stream>>>(
        q, ctxT, xr, xb, nullptr, nullptr, nullptr, nullptr, Sq,
        (long long)C * C, 0.044194173824159216f);

    // out = xr @ Wg.T + xr   (fp32 output; residual exact via MODE 3)
    gemm128<3, 2, false, 512><<<dim3(512), 512, 0, stream>>>(
        xr, wgb, out, xr, nullptr, nullptr, nullptr, nullptr, nullptr,
        0, 0.f);
}